// Round 1
// 306.983 us; speedup vs baseline: 1.5697x; 1.5697x over previous
//
#include <hip/hip_runtime.h>
#include <hip/hip_bf16.h>

typedef __attribute__((ext_vector_type(8)))  short bf16x8;   // 8 bf16 = 4 VGPRs
typedef __attribute__((ext_vector_type(16))) float f32x16;   // 32x32 MFMA accumulator

constexpr int Bn = 32, Cn = 64, Hn = 64, Wn = 256, On = 64, En = 4, Rn = 4;
constexpr float SCALE = 1.0f / Rn;

constexpr int WTILE  = 128;         // w per block
constexpr int HSTRIP = 8;           // output rows per block
constexpr int SLOT_B = 130 * 128;   // bytes per x-row ring slot (130 ww x 64 c x 2B)
constexpr int ROW_B  = 258 * 128;   // bytes per packed x row (b,h): 258 slots x 128B
constexpr int EPI_OS = 12;          // epilogue o-stride in floats (8 + pad, 16B-mult)

// ---------------------------------------------------------------------------
// Merge LoRA into conv weights, in 32x32x16 A-fragment order (unchanged):
// Wfrag[e][mh][s][lane][j]:  o = mh*32 + (lane&31),
//   k: tap = s>>2, c = (s&3)*16 + (lane>>5)*8 + j
// ---------------------------------------------------------------------------
__global__ __launch_bounds__(256) void merge_k(
    const float* __restrict__ Wc, const float* __restrict__ Wa,
    const float* __restrict__ Wb, __hip_bfloat16* __restrict__ Wfrag)
{
    int t = blockIdx.x * 256 + threadIdx.x;          // 0..147455 exact
    int j    = t & 7;
    int lane = (t >> 3) & 63;
    int g    = t >> 9;                               // (e*2+mh)*36 + s
    int s    = g % 36;
    int mh   = (g / 36) & 1;
    int e    = g / 72;
    int m = lane & 31, half = lane >> 5;
    int o = mh * 32 + m;
    int tap = s >> 2, cq = s & 3;
    int c = cq * 16 + half * 8 + j;
    float acc = Wc[(o * Cn + c) * 9 + tap];
#pragma unroll
    for (int r = 0; r < Rn; ++r)
        acc += SCALE * Wb[(e * On + o) * Rn + r] * Wa[((e * Rn + r) * Cn + c) * 9 + tap];
    Wfrag[t] = __float2bfloat16(acc);
}

// ---------------------------------------------------------------------------
// Pass 1: pack x (fp32 NCHW) -> xp (bf16, ring-slot layout, swizzle baked in).
// Per (b,h) row: 258 slots of 128B. Slot ww' holds c=0..63 of x[b][:][h][ww'-1],
// group cb at byte ((cb ^ (ww'&7))*16), bf16 i = c&7 inside the 16B group.
// Slots 0 (gw=-1) and 257 (gw=256) are zero (SAME padding halo).
// Main region: thread <-> (b, h, p, cb); p pairs slots (2p+1, 2p+2) so the 8
// per-c loads are aligned float2 and stores are 128B-chunked (full sectors).
// ---------------------------------------------------------------------------
__global__ __launch_bounds__(256) void pack_k(
    const float* __restrict__ x, __hip_bfloat16* __restrict__ xp)
{
    size_t g = (size_t)blockIdx.x * 256 + threadIdx.x;
    if (blockIdx.x < 8192) {
        int l  = (int)(g & 1023);
        int cb = l & 7;
        int p  = l >> 3;                 // 0..127
        int bh = (int)(g >> 10);         // b*64 + h, 0..2047
        const float* xr = x + ((size_t)(bh >> 6) * Cn * Hn + (bh & 63)) * Wn;
        union { __hip_bfloat16 u[8]; bf16x8 v; } u0, u1;
#pragma unroll
        for (int i = 0; i < 8; ++i) {
            int c = cb * 8 + i;
            float2 L = *reinterpret_cast<const float2*>(xr + (size_t)c * Hn * Wn + 2 * p);
            u0.u[i] = __float2bfloat16(L.x);
            u1.u[i] = __float2bfloat16(L.y);
        }
        char* row = (char*)xp + (size_t)bh * ROW_B;
        int s0 = 2 * p + 1, s1 = 2 * p + 2;
        *reinterpret_cast<bf16x8*>(row + s0 * 128 + ((cb ^ (s0 & 7)) * 16)) = u0.v;
        *reinterpret_cast<bf16x8*>(row + s1 * 128 + ((cb ^ (s1 & 7)) * 16)) = u1.v;
    } else {
        int z = (int)(g - (size_t)8192 * 256);       // 0..32767
        if (z < 32768) {
            int cb = z & 7, t = (z >> 3) & 1, bh = z >> 4;
            char* row = (char*)xp + (size_t)bh * ROW_B;
            bf16x8 zz = {};
            *reinterpret_cast<bf16x8*>(row + (t ? 257 : 0) * 128 + cb * 16) = zz;
        }
    }
}

// ---------------------------------------------------------------------------
// Pass 2: conv. Staging is now a straight 16.6KB window copy from xp (bf16,
// pre-swizzled): 4(+1 tail) dwordx4 loads -> regs -> ds_write_b128. No cvt,
// no boundary selects, 20 staging VGPRs instead of 40 -> no spill.
// Loads issued at iteration start, LDS writes after the epilogue (T14 split).
// ---------------------------------------------------------------------------
__global__ __launch_bounds__(256, 2) void conv2_k(
    const __hip_bfloat16* __restrict__ xp, const int* __restrict__ sid,
    const __hip_bfloat16* __restrict__ Wfrag, float* __restrict__ out)
{
    __shared__ __align__(16) char  xs[4 * SLOT_B];        // 66560 B ring
    __shared__ __align__(16) float ep[4 * 64 * EPI_OS];   // 12288 B epilogue

    const int tid = threadIdx.x;
    const int w0  = blockIdx.x * WTILE;
    const int h0  = blockIdx.y * HSTRIP;
    const int b   = blockIdx.z;
    const int e   = sid[b];

    const int lane = tid & 63, wave = tid >> 6;
    const int mh = wave & 1, nh = wave >> 1;
    const int n = lane & 31, half = lane >> 5;

    // A fragments: 36 x bf16x8, loaded once (L2-resident), live in VGPRs.
    bf16x8 wf[36];
    const bf16x8* wg = reinterpret_cast<const bf16x8*>(Wfrag) + (size_t)(e * 2 + mh) * 36 * 64;
#pragma unroll
    for (int s = 0; s < 36; ++s) wf[s] = wg[s * 64 + lane];

    float* epw = ep + wave * 64 * EPI_OS;

    // window of row (b,gh) for this w-tile starts at byte blockIdx.x*128*128
    const char* xwin = (const char*)xp + (size_t)b * Hn * ROW_B + (size_t)blockIdx.x * (WTILE * 128);

    uint4 stg[5];
    auto stage_load = [&](int rx) {
        const int gh = h0 + rx;
        if ((unsigned)gh < (unsigned)Hn) {
            const char* src = xwin + (size_t)gh * ROW_B;
#pragma unroll
            for (int r = 0; r < 4; ++r)
                stg[r] = *reinterpret_cast<const uint4*>(src + (r * 256 + tid) * 16);
            if (tid < 16)
                stg[4] = *reinterpret_cast<const uint4*>(src + 16384 + tid * 16);
        } else {
            uint4 zz = {0, 0, 0, 0};
#pragma unroll
            for (int r = 0; r < 5; ++r) stg[r] = zz;
        }
    };
    auto stage_store = [&](int rx) {
        const int slot = (rx + 1) & 3;
        char* d = xs + slot * SLOT_B;
#pragma unroll
        for (int r = 0; r < 4; ++r)
            *reinterpret_cast<uint4*>(d + (r * 256 + tid) * 16) = stg[r];
        if (tid < 16)
            *reinterpret_cast<uint4*>(d + 16384 + tid * 16) = stg[4];
    };

    // prologue: x rows h0-1, h0, h0+1
    stage_load(-1); stage_store(-1);
    stage_load(0);  stage_store(0);
    stage_load(1);  stage_store(1);
    __syncthreads();

    for (int st = 0; st < HSTRIP; ++st) {
        // 1. issue next row's global loads (hidden under compute + epilogue)
        const bool do_stage = (st + 2 <= HSTRIP);
        if (do_stage) stage_load(st + 2);

        // 2. compute output row h0+st
        f32x16 a[2];
#pragma unroll
        for (int nf = 0; nf < 2; ++nf)
#pragma unroll
            for (int i = 0; i < 16; ++i) a[nf][i] = 0.0f;

#pragma unroll
        for (int s = 0; s < 36; ++s) {
            const int tap = s >> 2, cq = s & 3;
            const int dh = tap / 3, dw = tap % 3;
            const int slotbase = ((st + dh) & 3) * SLOT_B;
#pragma unroll
            for (int nf = 0; nf < 2; ++nf) {
                int ww = nh * 64 + nf * 32 + n + dw;                 // 0..129
                int off = slotbase + ww * 128 + (((cq * 2 + half) ^ (ww & 7)) * 16);
                bf16x8 bf = *reinterpret_cast<const bf16x8*>(xs + off);
                a[nf] = __builtin_amdgcn_mfma_f32_32x32x16_bf16(wf[s], bf, a[nf], 0, 0, 0);
            }
        }

        // 3. epilogue: per-wave LDS transpose -> 256B-contiguous stores
        const int hrow = h0 + st;
#pragma unroll
        for (int t4 = 0; t4 < 4; ++t4) {
#pragma unroll
            for (int nf = 0; nf < 2; ++nf) {
                float4 v = make_float4(a[nf][4 * t4 + 0], a[nf][4 * t4 + 1],
                                       a[nf][4 * t4 + 2], a[nf][4 * t4 + 3]);
                *reinterpret_cast<float4*>(&epw[(nf * 32 + n) * EPI_OS + half * 4]) = v;
            }
#pragma unroll
            for (int k = 0; k < 4; ++k) {
                int mrel = 2 * k + half;           // 0..7
                int wbuf = 2 * n;                  // 0..62
                float lo = epw[wbuf * EPI_OS + mrel];
                float hi = epw[(wbuf + 1) * EPI_OS + mrel];
                int o = mh * 32 + 8 * t4 + mrel;
                size_t oidx = (((size_t)b * On + o) * Hn + hrow) * Wn + w0 + nh * 64 + wbuf;
                float2 v2; v2.x = lo; v2.y = hi;
                *reinterpret_cast<float2*>(&out[oidx]) = v2;
            }
        }

        // 4. write staged row to its ring slot (loads had compute+epilogue to land)
        if (do_stage) stage_store(st + 2);

        // 5. publish staged row / protect ring reuse
        __syncthreads();
    }
}

// ---------------------------------------------------------------------------
// Fallback: previous single-pass kernel (verbatim), used if ws is too small
// for the packed-x buffer.
// ---------------------------------------------------------------------------
__global__ __launch_bounds__(256, 2) void conv_k(
    const float* __restrict__ x, const int* __restrict__ sid,
    const __hip_bfloat16* __restrict__ Wfrag, float* __restrict__ out)
{
    __shared__ __align__(16) char  xs[4 * SLOT_B];
    __shared__ __align__(16) float ep[4 * 64 * EPI_OS];

    const int tid = threadIdx.x;
    const int w0  = blockIdx.x * WTILE;
    const int h0  = blockIdx.y * HSTRIP;
    const int b   = blockIdx.z;
    const int e   = sid[b];

    const int lane = tid & 63, wave = tid >> 6;
    const int mh = wave & 1, nh = wave >> 1;
    const int n = lane & 31, half = lane >> 5;

    bf16x8 wf[36];
    const bf16x8* wg = reinterpret_cast<const bf16x8*>(Wfrag) + (size_t)(e * 2 + mh) * 36 * 64;
#pragma unroll
    for (int s = 0; s < 36; ++s) wf[s] = wg[s * 64 + lane];

    float* epw = ep + wave * 64 * EPI_OS;

    float stg[5][8];
    auto stage_load = [&](int rx) {
        const int gh = h0 + rx;
        const bool ghv = (unsigned)gh < (unsigned)Hn;
#pragma unroll
        for (int r = 0; r < 5; ++r) {
            int t = r * 256 + tid;
            int cb = t >> 7, ww = t & 127;
            if (r == 4) { cb = (t - 1024) >> 1; ww = 128 + (t & 1); }
            bool active = (r < 4) || (tid < 16);
            int gw = w0 + ww - 1;
            bool v = active && ghv && ((unsigned)gw < (unsigned)Wn);
#pragma unroll
            for (int i = 0; i < 8; ++i)
                stg[r][i] = v ? x[(((size_t)b * Cn + cb * 8 + i) * Hn + gh) * Wn + gw] : 0.0f;
        }
    };
    auto stage_store = [&](int rx) {
        const int slot = (rx + 1) & 3;
#pragma unroll
        for (int r = 0; r < 5; ++r) {
            int t = r * 256 + tid;
            int cb = t >> 7, ww = t & 127;
            if (r == 4) { cb = (t - 1024) >> 1; ww = 128 + (t & 1); }
            bool active = (r < 4) || (tid < 16);
            if (!active) continue;
            union { __hip_bfloat16 u[8]; bf16x8 v8; } pk;
#pragma unroll
            for (int i = 0; i < 8; ++i) pk.u[i] = __float2bfloat16(stg[r][i]);
            int off = slot * SLOT_B + ww * 128 + ((cb ^ (ww & 7)) * 16);
            *reinterpret_cast<bf16x8*>(xs + off) = pk.v8;
        }
    };

    stage_load(-1); stage_store(-1);
    stage_load(0);  stage_store(0);
    stage_load(1);  stage_store(1);
    __syncthreads();

    for (int st = 0; st < HSTRIP; ++st) {
        const bool do_stage = (st + 2 <= HSTRIP);
        if (do_stage) stage_load(st + 2);

        f32x16 a[2];
#pragma unroll
        for (int nf = 0; nf < 2; ++nf)
#pragma unroll
            for (int i = 0; i < 16; ++i) a[nf][i] = 0.0f;

#pragma unroll
        for (int s = 0; s < 36; ++s) {
            const int tap = s >> 2, cq = s & 3;
            const int dh = tap / 3, dw = tap % 3;
            const int slotbase = ((st + dh) & 3) * SLOT_B;
#pragma unroll
            for (int nf = 0; nf < 2; ++nf) {
                int ww = nh * 64 + nf * 32 + n + dw;
                int off = slotbase + ww * 128 + (((cq * 2 + half) ^ (ww & 7)) * 16);
                bf16x8 bf = *reinterpret_cast<const bf16x8*>(xs + off);
                a[nf] = __builtin_amdgcn_mfma_f32_32x32x16_bf16(wf[s], bf, a[nf], 0, 0, 0);
            }
        }

        if (do_stage) stage_store(st + 2);

        const int hrow = h0 + st;
#pragma unroll
        for (int t4 = 0; t4 < 4; ++t4) {
#pragma unroll
            for (int nf = 0; nf < 2; ++nf) {
                float4 v = make_float4(a[nf][4 * t4 + 0], a[nf][4 * t4 + 1],
                                       a[nf][4 * t4 + 2], a[nf][4 * t4 + 3]);
                *reinterpret_cast<float4*>(&epw[(nf * 32 + n) * EPI_OS + half * 4]) = v;
            }
#pragma unroll
            for (int k = 0; k < 4; ++k) {
                int mrel = 2 * k + half;
                int wbuf = 2 * n;
                float lo = epw[wbuf * EPI_OS + mrel];
                float hi = epw[(wbuf + 1) * EPI_OS + mrel];
                int o = mh * 32 + 8 * t4 + mrel;
                size_t oidx = (((size_t)b * On + o) * Hn + hrow) * Wn + w0 + nh * 64 + wbuf;
                float2 v2; v2.x = lo; v2.y = hi;
                *reinterpret_cast<float2*>(&out[oidx]) = v2;
            }
        }

        __syncthreads();
    }
}

// ---------------------------------------------------------------------------
extern "C" void kernel_launch(void* const* d_in, const int* in_sizes, int n_in,
                              void* d_out, int out_size, void* d_ws, size_t ws_size,
                              hipStream_t stream)
{
    const float* x   = (const float*)d_in[0];
    const int*   sid = (const int*)d_in[1];
    const float* Wc  = (const float*)d_in[2];
    const float* Wa  = (const float*)d_in[3];
    const float* Wb  = (const float*)d_in[4];
    float*       out = (float*)d_out;

    __hip_bfloat16* Wfrag = (__hip_bfloat16*)d_ws;   // 294912 B
    const size_t WFRAG_B = 294912;
    const size_t XP_B    = (size_t)Bn * Hn * ROW_B;  // 67,633,152 B

    merge_k<<<En * 2 * 36 * 64 * 8 / 256, 256, 0, stream>>>(Wc, Wa, Wb, Wfrag);

    if (ws_size >= WFRAG_B + XP_B) {
        __hip_bfloat16* xp = (__hip_bfloat16*)((char*)d_ws + WFRAG_B);
        pack_k<<<8192 + 128, 256, 0, stream>>>(x, xp);
        dim3 grid(Wn / WTILE, Hn / HSTRIP, Bn);
        conv2_k<<<grid, 256, 0, stream>>>(xp, sid, Wfrag, out);
    } else {
        dim3 grid(Wn / WTILE, Hn / HSTRIP, Bn);
        conv_k<<<grid, 256, 0, stream>>>(x, sid, Wfrag, out);
    }
}

// Round 2
// 305.893 us; speedup vs baseline: 1.5753x; 1.0036x over previous
//
#include <hip/hip_runtime.h>
#include <hip/hip_bf16.h>

typedef __attribute__((ext_vector_type(8)))  short bf16x8;   // 8 bf16 = 4 VGPRs
typedef __attribute__((ext_vector_type(16))) float f32x16;   // 32x32 MFMA accumulator

constexpr int Bn = 32, Cn = 64, Hn = 64, Wn = 256, On = 64, En = 4, Rn = 4;
constexpr float SCALE = 1.0f / Rn;

constexpr int WTILE  = 128;         // w per block
constexpr int HSTRIP = 8;           // output rows per block
constexpr int SLOT_B = 130 * 128;   // bytes per x-row ring slot (130 ww x 64 c x 2B)
constexpr int EPI_OS = 12;          // epilogue o-stride in floats (8 + pad, 16B-mult)

// ---------------------------------------------------------------------------
// Merge LoRA into conv weights, in 32x32x16 A-fragment order (unchanged):
// Wfrag[e][mh][s][lane][j]:  o = mh*32 + (lane&31),
//   k: tap = s>>2, c = (s&3)*16 + (lane>>5)*8 + j
// ---------------------------------------------------------------------------
__global__ __launch_bounds__(256) void merge_k(
    const float* __restrict__ Wc, const float* __restrict__ Wa,
    const float* __restrict__ Wb, __hip_bfloat16* __restrict__ Wfrag)
{
    int t = blockIdx.x * 256 + threadIdx.x;          // 0..147455 exact
    int j    = t & 7;
    int lane = (t >> 3) & 63;
    int g    = t >> 9;                               // (e*2+mh)*36 + s
    int s    = g % 36;
    int mh   = (g / 36) & 1;
    int e    = g / 72;
    int m = lane & 31, half = lane >> 5;
    int o = mh * 32 + m;
    int tap = s >> 2, cq = s & 3;
    int c = cq * 16 + half * 8 + j;
    float acc = Wc[(o * Cn + c) * 9 + tap];
#pragma unroll
    for (int r = 0; r < Rn; ++r)
        acc += SCALE * Wb[(e * On + o) * Rn + r] * Wa[((e * Rn + r) * Cn + c) * 9 + tap];
    Wfrag[t] = __float2bfloat16(acc);
}

// ---------------------------------------------------------------------------
// Fused conv: reads fp32 x directly (no pack pass), stages via a register
// transpose. Thread = (cb = tid>>5, w-quad q = tid&31):
//   load: 8x global_load_dwordx4, c = cb*8+r, gw = w0+4q..+3  (512B segments)
//   hold f[8] across compute (T14 split), then cvt+pack 4x bf16x8 ->
//   ds_write_b128 into slots ww = 4q+1+j, group cb at ((cb^(ww&7))*16).
// Layout in LDS is byte-identical to the verified ring; MFMA loop and
// epilogue unchanged. Halo slots (ww=0, gw=w0-1) and (ww=129, gw=w0+128)
// handled by tid<16 with 8 strided scalar loads (512B/row total).
// Register budget: wf 144 + acc 32 + f 32 + hx 8 + addr ~25 = ~241 < 256.
// ---------------------------------------------------------------------------
__global__ __launch_bounds__(256, 2) void conv3_k(
    const float* __restrict__ x, const int* __restrict__ sid,
    const __hip_bfloat16* __restrict__ Wfrag, float* __restrict__ out)
{
    __shared__ __align__(16) char  xs[4 * SLOT_B];        // 66560 B ring
    __shared__ __align__(16) float ep[4 * 64 * EPI_OS];   // 12288 B epilogue

    const int tid = threadIdx.x;
    const int w0  = blockIdx.x * WTILE;
    const int h0  = blockIdx.y * HSTRIP;
    const int b   = blockIdx.z;
    const int e   = sid[b];

    const int lane = tid & 63, wave = tid >> 6;
    const int mh = wave & 1, nh = wave >> 1;
    const int n = lane & 31, half = lane >> 5;

    // A fragments: 36 x bf16x8, loaded once (L2-resident), live in VGPRs.
    bf16x8 wf[36];
    const bf16x8* wg = reinterpret_cast<const bf16x8*>(Wfrag) + (size_t)(e * 2 + mh) * 36 * 64;
#pragma unroll
    for (int s = 0; s < 36; ++s) wf[s] = wg[s * 64 + lane];

    float* epw = ep + wave * 64 * EPI_OS;

    // --- staging thread mapping ---
    const int cb = tid >> 5;                 // c-group 0..7
    const int q  = tid & 31;                 // w-quad 0..31
    const int side = (tid >> 3) & 1;         // tid<16: 0=left halo, 1=right halo
    const int hcb  = tid & 7;                // tid<16: halo c-group
    const float* xbase = x + ((size_t)b * Cn + cb * 8) * (size_t)(Hn * Wn) + w0 + 4 * q;
    const int gwh = side ? (w0 + WTILE) : (w0 - 1);
    const bool hv = (unsigned)gwh < (unsigned)Wn;
    const float* hbase = x + ((size_t)b * Cn + hcb * 8) * (size_t)(Hn * Wn) + gwh;

    float4 f[8];
    float  hx[8];

    auto stage_load = [&](int rx) {
        const int gh = h0 + rx;
        if ((unsigned)gh < (unsigned)Hn) {
            const float* src = xbase + (size_t)gh * Wn;
#pragma unroll
            for (int r = 0; r < 8; ++r)
                f[r] = *reinterpret_cast<const float4*>(src + (size_t)r * Hn * Wn);
            if (tid < 16) {
                if (hv) {
                    const float* hs = hbase + (size_t)gh * Wn;
#pragma unroll
                    for (int i = 0; i < 8; ++i) hx[i] = hs[(size_t)i * Hn * Wn];
                } else {
#pragma unroll
                    for (int i = 0; i < 8; ++i) hx[i] = 0.0f;
                }
            }
        } else {
            float4 z4 = make_float4(0.0f, 0.0f, 0.0f, 0.0f);
#pragma unroll
            for (int r = 0; r < 8; ++r) f[r] = z4;
            if (tid < 16) {
#pragma unroll
                for (int i = 0; i < 8; ++i) hx[i] = 0.0f;
            }
        }
    };
    auto stage_store = [&](int rx) {
        const int slot = (rx + 1) & 3;
        char* dbase = xs + slot * SLOT_B;
#pragma unroll
        for (int j = 0; j < 4; ++j) {
            union { __hip_bfloat16 u[8]; bf16x8 v; } pk;
#pragma unroll
            for (int r = 0; r < 8; ++r) {
                float v = (j == 0) ? f[r].x : (j == 1) ? f[r].y : (j == 2) ? f[r].z : f[r].w;
                pk.u[r] = __float2bfloat16(v);
            }
            int ww = 4 * q + 1 + j;          // 1..128
            *reinterpret_cast<bf16x8*>(dbase + ww * 128 + ((cb ^ (ww & 7)) * 16)) = pk.v;
        }
        if (tid < 16) {
            union { __hip_bfloat16 u[8]; bf16x8 v; } pk;
#pragma unroll
            for (int i = 0; i < 8; ++i) pk.u[i] = __float2bfloat16(hx[i]);
            int ww = side ? (WTILE + 1) : 0; // 129 or 0
            *reinterpret_cast<bf16x8*>(dbase + ww * 128 + ((hcb ^ (ww & 7)) * 16)) = pk.v;
        }
    };

    // prologue: x rows h0-1, h0, h0+1 -> slots 0,1,2
    stage_load(-1); stage_store(-1);
    stage_load(0);  stage_store(0);
    stage_load(1);  stage_store(1);
    __syncthreads();

    for (int st = 0; st < HSTRIP; ++st) {
        // 1. issue next row's global loads (hidden under compute + epilogue)
        const bool do_stage = (st + 2 <= HSTRIP);
        if (do_stage) stage_load(st + 2);

        // 2. compute output row h0+st
        f32x16 a[2];
#pragma unroll
        for (int nf = 0; nf < 2; ++nf)
#pragma unroll
            for (int i = 0; i < 16; ++i) a[nf][i] = 0.0f;

#pragma unroll
        for (int s = 0; s < 36; ++s) {
            const int tap = s >> 2, cq = s & 3;
            const int dh = tap / 3, dw = tap % 3;
            const int slotbase = ((st + dh) & 3) * SLOT_B;
#pragma unroll
            for (int nf = 0; nf < 2; ++nf) {
                int ww = nh * 64 + nf * 32 + n + dw;                 // 0..129
                int off = slotbase + ww * 128 + (((cq * 2 + half) ^ (ww & 7)) * 16);
                bf16x8 bf = *reinterpret_cast<const bf16x8*>(xs + off);
                a[nf] = __builtin_amdgcn_mfma_f32_32x32x16_bf16(wf[s], bf, a[nf], 0, 0, 0);
            }
        }

        // 3. epilogue: per-wave LDS transpose -> 256B-contiguous stores
        const int hrow = h0 + st;
#pragma unroll
        for (int t4 = 0; t4 < 4; ++t4) {
#pragma unroll
            for (int nf = 0; nf < 2; ++nf) {
                float4 v = make_float4(a[nf][4 * t4 + 0], a[nf][4 * t4 + 1],
                                       a[nf][4 * t4 + 2], a[nf][4 * t4 + 3]);
                *reinterpret_cast<float4*>(&epw[(nf * 32 + n) * EPI_OS + half * 4]) = v;
            }
#pragma unroll
            for (int k = 0; k < 4; ++k) {
                int mrel = 2 * k + half;           // 0..7
                int wbuf = 2 * n;                  // 0..62
                float lo = epw[wbuf * EPI_OS + mrel];
                float hi = epw[(wbuf + 1) * EPI_OS + mrel];
                int o = mh * 32 + 8 * t4 + mrel;
                size_t oidx = (((size_t)b * On + o) * Hn + hrow) * Wn + w0 + nh * 64 + wbuf;
                float2 v2; v2.x = lo; v2.y = hi;
                *reinterpret_cast<float2*>(&out[oidx]) = v2;
            }
        }

        // 4. cvt+pack staged row, write to its ring slot (loads have landed)
        if (do_stage) stage_store(st + 2);

        // 5. publish staged row / protect ring reuse
        __syncthreads();
    }
}

// ---------------------------------------------------------------------------
extern "C" void kernel_launch(void* const* d_in, const int* in_sizes, int n_in,
                              void* d_out, int out_size, void* d_ws, size_t ws_size,
                              hipStream_t stream)
{
    const float* x   = (const float*)d_in[0];
    const int*   sid = (const int*)d_in[1];
    const float* Wc  = (const float*)d_in[2];
    const float* Wa  = (const float*)d_in[3];
    const float* Wb  = (const float*)d_in[4];
    float*       out = (float*)d_out;

    __hip_bfloat16* Wfrag = (__hip_bfloat16*)d_ws;   // 294912 B, rewritten each call

    merge_k<<<En * 2 * 36 * 64 * 8 / 256, 256, 0, stream>>>(Wc, Wa, Wb, Wfrag);

    dim3 grid(Wn / WTILE, Hn / HSTRIP, Bn);
    conv3_k<<<grid, 256, 0, stream>>>(x, sid, Wfrag, out);
}

// Round 3
// 273.262 us; speedup vs baseline: 1.7634x; 1.1194x over previous
//
#include <hip/hip_runtime.h>
#include <hip/hip_bf16.h>

typedef __attribute__((ext_vector_type(8)))  short bf16x8;   // 8 bf16 = 4 VGPRs
typedef __attribute__((ext_vector_type(16))) float f32x16;   // 32x32 MFMA accumulator

constexpr int Bn = 32, Cn = 64, Hn = 64, Wn = 256, On = 64, En = 4, Rn = 4;
constexpr float SCALE = 1.0f / Rn;

constexpr int WTILE  = 128;         // w per block
constexpr int HSTRIP = 8;           // output rows per block
constexpr int SLOT_B = 130 * 128;   // bytes per x-row ring slot (130 ww x 64 c x 2B)

// Ring swizzle: 16B group of c-block cb in slot ww sits at byte
//   ww*128 + ((cb ^ ((ww>>2)&7)) * 16)
// Writes (lane q -> ww=4q+1+j): (ww>>2)&7 = (q+k)&7 spreads 8 groups -> conflict-free.
// Reads (lane n -> ww=base+n):   4 consecutive n share a group x8 groups x2 halves
//   = 8 lanes/group = b128 minimum -> conflict-free.
__device__ __forceinline__ int swz(int ww, int cb) {
    return ww * 128 + ((cb ^ ((ww >> 2) & 7)) * 16);
}

// ---------------------------------------------------------------------------
// Merge LoRA into conv weights, in 32x32x16 A-fragment order (unchanged):
// Wfrag[e][mh][s][lane][j]:  o = mh*32 + (lane&31),
//   k: tap = s>>2, c = (s&3)*16 + (lane>>5)*8 + j
// ---------------------------------------------------------------------------
__global__ __launch_bounds__(256) void merge_k(
    const float* __restrict__ Wc, const float* __restrict__ Wa,
    const float* __restrict__ Wb, __hip_bfloat16* __restrict__ Wfrag)
{
    int t = blockIdx.x * 256 + threadIdx.x;          // 0..147455 exact
    int j    = t & 7;
    int lane = (t >> 3) & 63;
    int g    = t >> 9;                               // (e*2+mh)*36 + s
    int s    = g % 36;
    int mh   = (g / 36) & 1;
    int e    = g / 72;
    int m = lane & 31, half = lane >> 5;
    int o = mh * 32 + m;
    int tap = s >> 2, cq = s & 3;
    int c = cq * 16 + half * 8 + j;
    float acc = Wc[(o * Cn + c) * 9 + tap];
#pragma unroll
    for (int r = 0; r < Rn; ++r)
        acc += SCALE * Wb[(e * On + o) * Rn + r] * Wa[((e * Rn + r) * Cn + c) * 9 + tap];
    Wfrag[t] = __float2bfloat16(acc);
}

// ---------------------------------------------------------------------------
// Fused conv, v4:
//  - ring swizzle on (ww>>2)&7: conflict-free staging writes AND reads
//  - epilogue: direct global_store_dword (full 128B segments per reg) — no ep LDS
//  - raw s_barrier + lgkmcnt(0) only (out-stores / staged loads float across)
//  - halo: 32 threads x 4 scalars (hx[4]) + ds_write_b64
// ---------------------------------------------------------------------------
__global__ __launch_bounds__(256, 2) void conv4_k(
    const float* __restrict__ x, const int* __restrict__ sid,
    const __hip_bfloat16* __restrict__ Wfrag, float* __restrict__ out)
{
    __shared__ __align__(16) char xs[4 * SLOT_B];        // 66560 B ring

    const int tid = threadIdx.x;
    const int w0  = blockIdx.x * WTILE;
    const int h0  = blockIdx.y * HSTRIP;
    const int b   = blockIdx.z;
    const int e   = sid[b];
    const size_t HW = (size_t)Hn * Wn;

    const int lane = tid & 63, wave = tid >> 6;
    const int mh = wave & 1, nh = wave >> 1;
    const int n = lane & 31, half = lane >> 5;

    // A fragments: 36 x bf16x8, loaded once (L2-resident), live in VGPRs.
    bf16x8 wf[36];
    const bf16x8* wg = reinterpret_cast<const bf16x8*>(Wfrag) + (size_t)(e * 2 + mh) * 36 * 64;
#pragma unroll
    for (int s = 0; s < 36; ++s) wf[s] = wg[s * 64 + lane];

    // --- staging thread mapping: thread = (cb = tid>>5, w-quad q = tid&31) ---
    const int cb = tid >> 5;                 // c-group 0..7
    const int q  = tid & 31;                 // w-quad 0..31
    const float* xbase = x + ((size_t)b * Cn + cb * 8) * HW + w0 + 4 * q;

    // halo mapping: 32 threads, 4 c each, ds_write_b64
    const int hside = tid >> 4;              // tid<32: 0=left (gw=w0-1), 1=right
    const int hidx  = tid & 15;
    const int hcb   = hidx >> 1, hhi = hidx & 1;
    const int gwh   = hside ? (w0 + WTILE) : (w0 - 1);
    const bool hv   = (unsigned)gwh < (unsigned)Wn;
    const float* hbase = x + ((size_t)b * Cn + hcb * 8 + hhi * 4) * HW + gwh;

    float4 f[8];
    float  hx[4];

    auto stage_load = [&](int rx) {
        const int gh = h0 + rx;
        if ((unsigned)gh < (unsigned)Hn) {
            const float* src = xbase + (size_t)gh * Wn;
#pragma unroll
            for (int r = 0; r < 8; ++r)
                f[r] = *reinterpret_cast<const float4*>(src + r * HW);
            if (tid < 32) {
                if (hv) {
                    const float* hs = hbase + (size_t)gh * Wn;
#pragma unroll
                    for (int i = 0; i < 4; ++i) hx[i] = hs[i * HW];
                } else {
#pragma unroll
                    for (int i = 0; i < 4; ++i) hx[i] = 0.0f;
                }
            }
        } else {
            float4 z4 = make_float4(0.0f, 0.0f, 0.0f, 0.0f);
#pragma unroll
            for (int r = 0; r < 8; ++r) f[r] = z4;
#pragma unroll
            for (int i = 0; i < 4; ++i) hx[i] = 0.0f;
        }
    };
    auto stage_store = [&](int rx) {
        const int slot = (rx + 1) & 3;
        char* dbase = xs + slot * SLOT_B;
#pragma unroll
        for (int j = 0; j < 4; ++j) {
            union { __hip_bfloat16 u[8]; bf16x8 v; } pk;
#pragma unroll
            for (int r = 0; r < 8; ++r) {
                float v = (j == 0) ? f[r].x : (j == 1) ? f[r].y : (j == 2) ? f[r].z : f[r].w;
                pk.u[r] = __float2bfloat16(v);
            }
            int ww = 4 * q + 1 + j;          // 1..128
            *reinterpret_cast<bf16x8*>(dbase + swz(ww, cb)) = pk.v;
        }
        if (tid < 32) {
            union { __hip_bfloat16 u[4]; short4 v; } pk;
#pragma unroll
            for (int i = 0; i < 4; ++i) pk.u[i] = __float2bfloat16(hx[i]);
            int ww = hside ? (WTILE + 1) : 0;        // 129 or 0; (ww>>2)&7 == 0
            *reinterpret_cast<short4*>(dbase + swz(ww, hcb) + hhi * 8) = pk.v;
        }
    };

    auto barrier = [&]() {
        asm volatile("s_waitcnt lgkmcnt(0)" ::: "memory");
        __builtin_amdgcn_s_barrier();
    };

    // prologue: x rows h0-1, h0, h0+1 -> slots 0,1,2
    stage_load(-1); stage_store(-1);
    stage_load(0);  stage_store(0);
    stage_load(1);  stage_store(1);
    barrier();

    for (int st = 0; st < HSTRIP; ++st) {
        // 1. issue next row's global loads (hidden under compute + epilogue)
        const bool do_stage = (st + 2 <= HSTRIP);
        if (do_stage) stage_load(st + 2);

        // 2. compute output row h0+st
        f32x16 a[2];
#pragma unroll
        for (int nf = 0; nf < 2; ++nf)
#pragma unroll
            for (int i = 0; i < 16; ++i) a[nf][i] = 0.0f;

#pragma unroll
        for (int s = 0; s < 36; ++s) {
            const int tap = s >> 2, cq = s & 3;
            const int dh = tap / 3, dw = tap % 3;
            const int slotbase = ((st + dh) & 3) * SLOT_B;
#pragma unroll
            for (int nf = 0; nf < 2; ++nf) {
                int ww = nh * 64 + nf * 32 + n + dw;                 // 0..129
                bf16x8 bf = *reinterpret_cast<const bf16x8*>(xs + slotbase + swz(ww, cq * 2 + half));
                a[nf] = __builtin_amdgcn_mfma_f32_32x32x16_bf16(wf[s], bf, a[nf], 0, 0, 0);
            }
        }

        // 3. epilogue: direct global stores. For fixed reg: lanes n=0..31 cover
        //    128B contiguous at (o = mh*32 + 4*half + (r&3)+8*(r>>2), row hrow).
        {
            const int hrow = h0 + st;
            size_t base = ((size_t)(b * On + mh * 32 + 4 * half) * Hn + hrow) * Wn
                          + w0 + nh * 64 + n;
#pragma unroll
            for (int nf = 0; nf < 2; ++nf)
#pragma unroll
                for (int r = 0; r < 16; ++r) {
                    int o_off = (r & 3) + 8 * (r >> 2);
                    out[base + (size_t)o_off * HW + nf * 32] = a[nf][r];
                }
        }

        // 4. cvt+pack staged row, write to its ring slot (loads have landed)
        if (do_stage) stage_store(st + 2);

        // 5. publish staged row / protect ring reuse (LDS-only fence + barrier;
        //    out-stores and next loads stay in flight)
        barrier();
    }
}

// ---------------------------------------------------------------------------
extern "C" void kernel_launch(void* const* d_in, const int* in_sizes, int n_in,
                              void* d_out, int out_size, void* d_ws, size_t ws_size,
                              hipStream_t stream)
{
    const float* x   = (const float*)d_in[0];
    const int*   sid = (const int*)d_in[1];
    const float* Wc  = (const float*)d_in[2];
    const float* Wa  = (const float*)d_in[3];
    const float* Wb  = (const float*)d_in[4];
    float*       out = (float*)d_out;

    __hip_bfloat16* Wfrag = (__hip_bfloat16*)d_ws;   // 294912 B, rewritten each call

    merge_k<<<En * 2 * 36 * 64 * 8 / 256, 256, 0, stream>>>(Wc, Wa, Wb, Wfrag);

    dim3 grid(Wn / WTILE, Hn / HSTRIP, Bn);
    conv4_k<<<grid, 256, 0, stream>>>(x, sid, Wfrag, out);
}

// Round 4
// 270.375 us; speedup vs baseline: 1.7823x; 1.0107x over previous
//
#include <hip/hip_runtime.h>
#include <hip/hip_bf16.h>

typedef __attribute__((ext_vector_type(8)))  short bf16x8;   // 8 bf16 = 4 VGPRs
typedef __attribute__((ext_vector_type(16))) float f32x16;   // 32x32 MFMA accumulator

constexpr int Bn = 32, Cn = 64, Hn = 64, Wn = 256, On = 64, En = 4, Rn = 4;
constexpr float SCALE = 1.0f / Rn;

constexpr int WTILE  = 128;         // w per block
constexpr int HSTRIP = 8;           // output rows per block
constexpr int SLOT_B = 130 * 128;   // bytes per x-row ring slot (130 ww x 64 c x 2B)

// Ring swizzle: 16B group of c-block cb in slot ww sits at byte
//   ww*128 + ((cb ^ ((ww>>2)&7)) * 16)
// Writes (lane q -> ww=4q+1+j): (ww>>2)&7 = (q+k)&7 spreads 8 groups -> conflict-free.
// Reads (lane n -> ww=base+n):   4 consecutive n share a group x8 groups x2 halves
//   = 8 lanes/group = b128 minimum -> conflict-free.
__device__ __forceinline__ int swz(int ww, int cb) {
    return ww * 128 + ((cb ^ ((ww >> 2) & 7)) * 16);
}

// ---------------------------------------------------------------------------
// Merge LoRA into conv weights, in 32x32x16 A-fragment order (unchanged):
// Wfrag[e][mh][s][lane][j]:  o = mh*32 + (lane&31),
//   k: tap = s>>2, c = (s&3)*16 + (lane>>5)*8 + j
// ---------------------------------------------------------------------------
__global__ __launch_bounds__(256) void merge_k(
    const float* __restrict__ Wc, const float* __restrict__ Wa,
    const float* __restrict__ Wb, __hip_bfloat16* __restrict__ Wfrag)
{
    int t = blockIdx.x * 256 + threadIdx.x;          // 0..147455 exact
    int j    = t & 7;
    int lane = (t >> 3) & 63;
    int g    = t >> 9;                               // (e*2+mh)*36 + s
    int s    = g % 36;
    int mh   = (g / 36) & 1;
    int e    = g / 72;
    int m = lane & 31, half = lane >> 5;
    int o = mh * 32 + m;
    int tap = s >> 2, cq = s & 3;
    int c = cq * 16 + half * 8 + j;
    float acc = Wc[(o * Cn + c) * 9 + tap];
#pragma unroll
    for (int r = 0; r < Rn; ++r)
        acc += SCALE * Wb[(e * On + o) * Rn + r] * Wa[((e * Rn + r) * Cn + c) * 9 + tap];
    Wfrag[t] = __float2bfloat16(acc);
}

// ---------------------------------------------------------------------------
// Fused conv, v5: identical to v4 except the per-iteration schedule is
//   [loads(st+2) | compute(st) | stage_store(st+2) | out-stores(st) | barrier]
// (stage_store moved BEFORE the epilogue). Rationale: vmcnt retires in order,
// so v4's wait-for-loads at stage_store had to drain the 32 output stores
// issued moments earlier (HBM write ack ~1k+ cyc) every iteration, right
// before the barrier. Now the wait sees only the PREVIOUS iteration's stores
// (a full compute phase old). Race-free: stage_store(st+2) writes slot
// (st+3)&3, disjoint from compute(st)'s read slots {st,st+1,st+2}&3; the
// prior reader of that slot was protected by the previous barrier.
// ---------------------------------------------------------------------------
__global__ __launch_bounds__(256, 2) void conv5_k(
    const float* __restrict__ x, const int* __restrict__ sid,
    const __hip_bfloat16* __restrict__ Wfrag, float* __restrict__ out)
{
    __shared__ __align__(16) char xs[4 * SLOT_B];        // 66560 B ring

    const int tid = threadIdx.x;
    const int w0  = blockIdx.x * WTILE;
    const int h0  = blockIdx.y * HSTRIP;
    const int b   = blockIdx.z;
    const int e   = sid[b];
    const size_t HW = (size_t)Hn * Wn;

    const int lane = tid & 63, wave = tid >> 6;
    const int mh = wave & 1, nh = wave >> 1;
    const int n = lane & 31, half = lane >> 5;

    // A fragments: 36 x bf16x8, loaded once (L2-resident), live in VGPRs/AGPRs.
    bf16x8 wf[36];
    const bf16x8* wg = reinterpret_cast<const bf16x8*>(Wfrag) + (size_t)(e * 2 + mh) * 36 * 64;
#pragma unroll
    for (int s = 0; s < 36; ++s) wf[s] = wg[s * 64 + lane];

    // --- staging thread mapping: thread = (cb = tid>>5, w-quad q = tid&31) ---
    const int cb = tid >> 5;                 // c-group 0..7
    const int q  = tid & 31;                 // w-quad 0..31
    const float* xbase = x + ((size_t)b * Cn + cb * 8) * HW + w0 + 4 * q;

    // halo mapping: 32 threads, 4 c each, ds_write_b64
    const int hside = tid >> 4;              // tid<32: 0=left (gw=w0-1), 1=right
    const int hidx  = tid & 15;
    const int hcb   = hidx >> 1, hhi = hidx & 1;
    const int gwh   = hside ? (w0 + WTILE) : (w0 - 1);
    const bool hv   = (unsigned)gwh < (unsigned)Wn;
    const float* hbase = x + ((size_t)b * Cn + hcb * 8 + hhi * 4) * HW + gwh;

    float4 f[8];
    float  hx[4];

    auto stage_load = [&](int rx) {
        const int gh = h0 + rx;
        if ((unsigned)gh < (unsigned)Hn) {
            const float* src = xbase + (size_t)gh * Wn;
#pragma unroll
            for (int r = 0; r < 8; ++r)
                f[r] = *reinterpret_cast<const float4*>(src + r * HW);
            if (tid < 32) {
                if (hv) {
                    const float* hs = hbase + (size_t)gh * Wn;
#pragma unroll
                    for (int i = 0; i < 4; ++i) hx[i] = hs[i * HW];
                } else {
#pragma unroll
                    for (int i = 0; i < 4; ++i) hx[i] = 0.0f;
                }
            }
        } else {
            float4 z4 = make_float4(0.0f, 0.0f, 0.0f, 0.0f);
#pragma unroll
            for (int r = 0; r < 8; ++r) f[r] = z4;
#pragma unroll
            for (int i = 0; i < 4; ++i) hx[i] = 0.0f;
        }
    };
    auto stage_store = [&](int rx) {
        const int slot = (rx + 1) & 3;
        char* dbase = xs + slot * SLOT_B;
#pragma unroll
        for (int j = 0; j < 4; ++j) {
            union { __hip_bfloat16 u[8]; bf16x8 v; } pk;
#pragma unroll
            for (int r = 0; r < 8; ++r) {
                float v = (j == 0) ? f[r].x : (j == 1) ? f[r].y : (j == 2) ? f[r].z : f[r].w;
                pk.u[r] = __float2bfloat16(v);
            }
            int ww = 4 * q + 1 + j;          // 1..128
            *reinterpret_cast<bf16x8*>(dbase + swz(ww, cb)) = pk.v;
        }
        if (tid < 32) {
            union { __hip_bfloat16 u[4]; short4 v; } pk;
#pragma unroll
            for (int i = 0; i < 4; ++i) pk.u[i] = __float2bfloat16(hx[i]);
            int ww = hside ? (WTILE + 1) : 0;        // 129 or 0; (ww>>2)&7 == 0
            *reinterpret_cast<short4*>(dbase + swz(ww, hcb) + hhi * 8) = pk.v;
        }
    };

    auto barrier = [&]() {
        asm volatile("s_waitcnt lgkmcnt(0)" ::: "memory");
        __builtin_amdgcn_s_barrier();
    };

    // prologue: x rows h0-1, h0, h0+1 -> slots 0,1,2
    stage_load(-1); stage_store(-1);
    stage_load(0);  stage_store(0);
    stage_load(1);  stage_store(1);
    barrier();

    for (int st = 0; st < HSTRIP; ++st) {
        // 1. issue next row's global loads (land during compute)
        const bool do_stage = (st + 2 <= HSTRIP);
        if (do_stage) stage_load(st + 2);

        // 2. compute output row h0+st
        f32x16 a[2];
#pragma unroll
        for (int nf = 0; nf < 2; ++nf)
#pragma unroll
            for (int i = 0; i < 16; ++i) a[nf][i] = 0.0f;

#pragma unroll
        for (int s = 0; s < 36; ++s) {
            const int tap = s >> 2, cq = s & 3;
            const int dh = tap / 3, dw = tap % 3;
            const int slotbase = ((st + dh) & 3) * SLOT_B;
#pragma unroll
            for (int nf = 0; nf < 2; ++nf) {
                int ww = nh * 64 + nf * 32 + n + dw;                 // 0..129
                bf16x8 bf = *reinterpret_cast<const bf16x8*>(xs + slotbase + swz(ww, cq * 2 + half));
                a[nf] = __builtin_amdgcn_mfma_f32_32x32x16_bf16(wf[s], bf, a[nf], 0, 0, 0);
            }
        }

        // 3. cvt+pack staged row -> ring slot (st+3)&3. Wait-for-loads here
        //    only has the PREVIOUS iteration's out-stores ahead of it.
        if (do_stage) stage_store(st + 2);

        // 4. epilogue: direct global stores (never waited on this iteration).
        //    For fixed reg: lanes n=0..31 cover 128B contiguous at
        //    (o = mh*32 + 4*half + (r&3)+8*(r>>2), row hrow).
        {
            const int hrow = h0 + st;
            size_t base = ((size_t)(b * On + mh * 32 + 4 * half) * Hn + hrow) * Wn
                          + w0 + nh * 64 + n;
#pragma unroll
            for (int nf = 0; nf < 2; ++nf)
#pragma unroll
                for (int r = 0; r < 16; ++r) {
                    int o_off = (r & 3) + 8 * (r >> 2);
                    out[base + (size_t)o_off * HW + nf * 32] = a[nf][r];
                }
        }

        // 5. publish staged row / protect ring reuse (LDS-only fence + barrier;
        //    out-stores and next loads stay in flight)
        barrier();
    }
}

// ---------------------------------------------------------------------------
extern "C" void kernel_launch(void* const* d_in, const int* in_sizes, int n_in,
                              void* d_out, int out_size, void* d_ws, size_t ws_size,
                              hipStream_t stream)
{
    const float* x   = (const float*)d_in[0];
    const int*   sid = (const int*)d_in[1];
    const float* Wc  = (const float*)d_in[2];
    const float* Wa  = (const float*)d_in[3];
    const float* Wb  = (const float*)d_in[4];
    float*       out = (float*)d_out;

    __hip_bfloat16* Wfrag = (__hip_bfloat16*)d_ws;   // 294912 B, rewritten each call

    merge_k<<<En * 2 * 36 * 64 * 8 / 256, 256, 0, stream>>>(Wc, Wa, Wb, Wfrag);

    dim3 grid(Wn / WTILE, Hn / HSTRIP, Bn);
    conv5_k<<<grid, 256, 0, stream>>>(x, sid, Wfrag, out);
}